// Round 1
// baseline (419.480 us; speedup 1.0000x reference)
//
#include <hip/hip_runtime.h>

#define NN 2048
#define BB 16
#define TT 256

typedef unsigned short ushort_t;
typedef short bf16x8 __attribute__((ext_vector_type(8)));
typedef float f32x4 __attribute__((ext_vector_type(4)));

__device__ __forceinline__ ushort_t f2bf(float f) {
    unsigned u = __float_as_uint(f);
    return (ushort_t)((u + 0x7FFFu + ((u >> 16) & 1u)) >> 16);  // RNE
}

// K1: column-sum over batch: xsumT[t][n] = sum_b x[b][t][n]   (mean scale cancels)
__global__ __launch_bounds__(256) void k_colsum(const float* __restrict__ x,
                                                float* __restrict__ xsumT) {
    const int n = blockIdx.x * 256 + threadIdx.x;
    const int t = blockIdx.y;
    float s = 0.f;
#pragma unroll
    for (int b = 0; b < BB; b++) s += x[(size_t)(b * TT + t) * NN + n];
    xsumT[(size_t)t * NN + n] = s;
}

// K2: inv_norm[n] = 1/||xsum_n||  (norm clamp at 1e-12 never active in practice)
__global__ __launch_bounds__(256) void k_invnorm(const float* __restrict__ xsumT,
                                                 float* __restrict__ inv_norm) {
    const int n = blockIdx.x * 256 + threadIdx.x;
    float ss = 0.f;
    for (int t = 0; t < TT; t++) { float v = xsumT[(size_t)t * NN + n]; ss += v * v; }
    inv_norm[n] = (ss > 0.f) ? rsqrtf(ss) : 0.f;
}

// K3: sim GEMM (fp32, K=256) + gumbel comparator -> adj (0/1 fp32)
// adj[i][j] = dot(xn_i, xn_j) > g1 - g0
__global__ __launch_bounds__(256) void k_adj(const float* __restrict__ A,
                                             const float* __restrict__ inv_norm,
                                             const float* __restrict__ gumbel,
                                             float* __restrict__ adj) {
    __shared__ float As[8][128];
    __shared__ float Bs[8][128];
    const int m0 = blockIdx.y * 128, n0 = blockIdx.x * 128;
    const int tid = threadIdx.x;
    const int tx = tid & 15, ty = tid >> 4;
    const int lr = tid >> 5, lc = (tid & 31) * 4;
    float acc[8][8];
#pragma unroll
    for (int i = 0; i < 8; i++)
#pragma unroll
        for (int j = 0; j < 8; j++) acc[i][j] = 0.f;
    for (int k0 = 0; k0 < TT; k0 += 8) {
        float4 av = *(const float4*)&A[(size_t)(k0 + lr) * NN + m0 + lc];
        float4 bv = *(const float4*)&A[(size_t)(k0 + lr) * NN + n0 + lc];
        __syncthreads();
        *(float4*)&As[lr][lc] = av;
        *(float4*)&Bs[lr][lc] = bv;
        __syncthreads();
#pragma unroll
        for (int kk = 0; kk < 8; kk++) {
            float a[8], b[8];
            *(float4*)&a[0] = *(const float4*)&As[kk][ty * 8];
            *(float4*)&a[4] = *(const float4*)&As[kk][ty * 8 + 4];
            *(float4*)&b[0] = *(const float4*)&Bs[kk][tx * 8];
            *(float4*)&b[4] = *(const float4*)&Bs[kk][tx * 8 + 4];
#pragma unroll
            for (int i = 0; i < 8; i++)
#pragma unroll
                for (int j = 0; j < 8; j++) acc[i][j] = fmaf(a[i], b[j], acc[i][j]);
        }
    }
#pragma unroll
    for (int i = 0; i < 8; i++) {
        const int gi = m0 + ty * 8 + i;
        const float invi = inv_norm[gi];
#pragma unroll
        for (int j = 0; j < 8; j++) {
            const int gj = n0 + tx * 8 + j;
            const float dot = acc[i][j] * invi * inv_norm[gj];
            const size_t fl = (size_t)gi * NN + gj;
            const float2 g = *(const float2*)&gumbel[2 * fl];
            adj[fl] = (dot > g.y - g.x) ? 1.f : 0.f;
        }
    }
}

// K4: nmask = clip(adj + adjT + I, 0, 1) as bf16 (exact 0/1)
__global__ __launch_bounds__(256) void k_nmask(const float* __restrict__ adj,
                                               ushort_t* __restrict__ nm) {
    __shared__ float tt[32][33];
    const int J = blockIdx.x * 32, I = blockIdx.y * 32;
    const int c = threadIdx.x & 31, r0 = threadIdx.x >> 5;  // 8 row-groups
#pragma unroll
    for (int r = r0; r < 32; r += 8) tt[r][c] = adj[(size_t)(J + r) * NN + I + c];
    __syncthreads();
#pragma unroll
    for (int r = r0; r < 32; r += 8) {
        const int gi = I + r, gj = J + c;
        float v;
        if (gi == gj) v = 1.f;
        else v = fminf(adj[(size_t)gi * NN + gj] + tt[c][r], 1.f);
        nm[(size_t)gi * NN + gj] = (v > 0.5f) ? (ushort_t)0x3F80 : (ushort_t)0;
    }
}

// K5: common = nmask @ nmask (bf16 MFMA, integer-exact) fused with
//     W[i][j] = adj[i][j] * (common>1) * common^2     (max_common cancels in Wn)
__global__ __launch_bounds__(256) void k_commonW(const ushort_t* __restrict__ nm,
                                                 const float* __restrict__ adj,
                                                 float* __restrict__ W) {
    __shared__ ushort_t As[128][32];
    __shared__ ushort_t Bs[128][32];
    const int m0 = blockIdx.y * 128, n0 = blockIdx.x * 128;
    const int tid = threadIdx.x;
    const int lane = tid & 63, wave = tid >> 6;
    const int wr = wave >> 1, wc = wave & 1;
    f32x4 acc[4][4];
#pragma unroll
    for (int i = 0; i < 4; i++)
#pragma unroll
        for (int j = 0; j < 4; j++) acc[i][j] = (f32x4){0.f, 0.f, 0.f, 0.f};
    const int r0 = tid >> 2, kc = (tid & 3) * 8;  // rows 0..63 ; +64 for 2nd chunk
    for (int k0 = 0; k0 < NN; k0 += 32) {
        uint4 a0 = *(const uint4*)&nm[(size_t)(m0 + r0) * NN + k0 + kc];
        uint4 b0 = *(const uint4*)&nm[(size_t)(n0 + r0) * NN + k0 + kc];
        uint4 a1 = *(const uint4*)&nm[(size_t)(m0 + r0 + 64) * NN + k0 + kc];
        uint4 b1 = *(const uint4*)&nm[(size_t)(n0 + r0 + 64) * NN + k0 + kc];
        __syncthreads();
        *(uint4*)&As[r0][kc] = a0;      *(uint4*)&Bs[r0][kc] = b0;
        *(uint4*)&As[r0 + 64][kc] = a1; *(uint4*)&Bs[r0 + 64][kc] = b1;
        __syncthreads();
        const int lr = lane & 15, kg = (lane >> 4) * 8;
        bf16x8 af[4], bff[4];
#pragma unroll
        for (int f = 0; f < 4; f++) {
            af[f]  = *(const bf16x8*)&As[wr * 64 + f * 16 + lr][kg];
            bff[f] = *(const bf16x8*)&Bs[wc * 64 + f * 16 + lr][kg];
        }
#pragma unroll
        for (int i = 0; i < 4; i++)
#pragma unroll
            for (int j = 0; j < 4; j++)
                acc[i][j] = __builtin_amdgcn_mfma_f32_16x16x32_bf16(af[i], bff[j], acc[i][j], 0, 0, 0);
    }
    const int lr = lane & 15, rg = (lane >> 4) * 4;
#pragma unroll
    for (int i = 0; i < 4; i++)
#pragma unroll
        for (int j = 0; j < 4; j++)
#pragma unroll
            for (int r = 0; r < 4; r++) {
                const int gi = m0 + wr * 64 + i * 16 + rg + r;
                const int gj = n0 + wc * 64 + j * 16 + lr;
                const float cv = acc[i][j][r];
                const size_t fl = (size_t)gi * NN + gj;
                W[fl] = (cv > 1.0f) ? adj[fl] * cv * cv : 0.f;
            }
}

// K6: dinv[d] = deg[d]>0 ? deg^-1/2 : 0,  deg[d] = sum_s W[s][d]
__global__ __launch_bounds__(256) void k_dinv(const float* __restrict__ W,
                                              float* __restrict__ dinv) {
    const int d = blockIdx.x * 256 + threadIdx.x;
    float s = 0.f;
    for (int src = 0; src < NN; src++) s += W[(size_t)src * NN + d];
    dinv[d] = (s > 0.f) ? rsqrtf(s) : 0.f;
}

// K7: Wtn[d][s] = bf16( dinv[s] * W[s][d] * dinv[d] )   (transpose + scale)
__global__ __launch_bounds__(256) void k_wtn(const float* __restrict__ W,
                                             const float* __restrict__ dinv,
                                             ushort_t* __restrict__ Wtn) {
    __shared__ float tt[64][65];
    const int S0 = blockIdx.x * 64, D0 = blockIdx.y * 64;
    const int c = threadIdx.x & 63, r0 = threadIdx.x >> 6;  // 4 row-groups
#pragma unroll
    for (int r = r0; r < 64; r += 4) tt[r][c] = W[(size_t)(S0 + r) * NN + D0 + c];
    __syncthreads();
    const float ds = dinv[S0 + c];
#pragma unroll
    for (int r = r0; r < 64; r += 4) {
        const int d = D0 + r;
        Wtn[(size_t)d * NN + S0 + c] = f2bf(tt[c][r] * ds * dinv[d]);
    }
}

// K8: per-batch GEMM (fp32): xwT[b][o][n] = sum_t w[t][o] * x[b][t][n], stored bf16
__global__ __launch_bounds__(256) void k_xw(const float* __restrict__ w,
                                            const float* __restrict__ x,
                                            ushort_t* __restrict__ xwT) {
    __shared__ float As[8][128];
    __shared__ float Bs[8][128];
    const int b = blockIdx.z;
    const float* __restrict__ Bp = x + (size_t)b * TT * NN;
    const int m0 = blockIdx.y * 128, n0 = blockIdx.x * 128;
    const int tid = threadIdx.x;
    const int tx = tid & 15, ty = tid >> 4;
    const int lr = tid >> 5, lc = (tid & 31) * 4;
    float acc[8][8];
#pragma unroll
    for (int i = 0; i < 8; i++)
#pragma unroll
        for (int j = 0; j < 8; j++) acc[i][j] = 0.f;
    for (int k0 = 0; k0 < TT; k0 += 8) {
        float4 av = *(const float4*)&w[(size_t)(k0 + lr) * TT + m0 + lc];
        float4 bv = *(const float4*)&Bp[(size_t)(k0 + lr) * NN + n0 + lc];
        __syncthreads();
        *(float4*)&As[lr][lc] = av;
        *(float4*)&Bs[lr][lc] = bv;
        __syncthreads();
#pragma unroll
        for (int kk = 0; kk < 8; kk++) {
            float a[8], bb[8];
            *(float4*)&a[0]  = *(const float4*)&As[kk][ty * 8];
            *(float4*)&a[4]  = *(const float4*)&As[kk][ty * 8 + 4];
            *(float4*)&bb[0] = *(const float4*)&Bs[kk][tx * 8];
            *(float4*)&bb[4] = *(const float4*)&Bs[kk][tx * 8 + 4];
#pragma unroll
            for (int i = 0; i < 8; i++)
#pragma unroll
                for (int j = 0; j < 8; j++) acc[i][j] = fmaf(a[i], bb[j], acc[i][j]);
        }
    }
#pragma unroll
    for (int i = 0; i < 8; i++) {
        const int o = m0 + ty * 8 + i;
#pragma unroll
        for (int j = 0; j < 8; j++) {
            const int n = n0 + tx * 8 + j;
            xwT[((size_t)b * TT + o) * NN + n] = f2bf(acc[i][j]);
        }
    }
}

// K9: out[bt][d] = sum_s xwT[bt][s] * Wtn[d][s] + bias[bt%T]  (bf16 MFMA)
// writes d_out directly in [B,T,N] layout
__global__ __launch_bounds__(256) void k_out(const ushort_t* __restrict__ xwT,
                                             const ushort_t* __restrict__ Wtn,
                                             const float* __restrict__ bias,
                                             float* __restrict__ out) {
    __shared__ ushort_t As[128][32];
    __shared__ ushort_t Bs[128][32];
    const int m0 = blockIdx.y * 128, n0 = blockIdx.x * 128;
    const int tid = threadIdx.x;
    const int lane = tid & 63, wave = tid >> 6;
    const int wr = wave >> 1, wc = wave & 1;
    f32x4 acc[4][4];
#pragma unroll
    for (int i = 0; i < 4; i++)
#pragma unroll
        for (int j = 0; j < 4; j++) acc[i][j] = (f32x4){0.f, 0.f, 0.f, 0.f};
    const int r0 = tid >> 2, kc = (tid & 3) * 8;
    for (int k0 = 0; k0 < NN; k0 += 32) {
        uint4 a0 = *(const uint4*)&xwT[(size_t)(m0 + r0) * NN + k0 + kc];
        uint4 b0 = *(const uint4*)&Wtn[(size_t)(n0 + r0) * NN + k0 + kc];
        uint4 a1 = *(const uint4*)&xwT[(size_t)(m0 + r0 + 64) * NN + k0 + kc];
        uint4 b1 = *(const uint4*)&Wtn[(size_t)(n0 + r0 + 64) * NN + k0 + kc];
        __syncthreads();
        *(uint4*)&As[r0][kc] = a0;      *(uint4*)&Bs[r0][kc] = b0;
        *(uint4*)&As[r0 + 64][kc] = a1; *(uint4*)&Bs[r0 + 64][kc] = b1;
        __syncthreads();
        const int lr = lane & 15, kg = (lane >> 4) * 8;
        bf16x8 af[4], bff[4];
#pragma unroll
        for (int f = 0; f < 4; f++) {
            af[f]  = *(const bf16x8*)&As[wr * 64 + f * 16 + lr][kg];
            bff[f] = *(const bf16x8*)&Bs[wc * 64 + f * 16 + lr][kg];
        }
#pragma unroll
        for (int i = 0; i < 4; i++)
#pragma unroll
            for (int j = 0; j < 4; j++)
                acc[i][j] = __builtin_amdgcn_mfma_f32_16x16x32_bf16(af[i], bff[j], acc[i][j], 0, 0, 0);
    }
    const int lr = lane & 15, rg = (lane >> 4) * 4;
#pragma unroll
    for (int i = 0; i < 4; i++)
#pragma unroll
        for (int j = 0; j < 4; j++)
#pragma unroll
            for (int r = 0; r < 4; r++) {
                const int gm = m0 + wr * 64 + i * 16 + rg + r;  // bt
                const int gd = n0 + wc * 64 + j * 16 + lr;      // node d
                out[(size_t)gm * NN + gd] = acc[i][j][r] + bias[gm & (TT - 1)];
            }
}

extern "C" void kernel_launch(void* const* d_in, const int* in_sizes, int n_in,
                              void* d_out, int out_size, void* d_ws, size_t ws_size,
                              hipStream_t stream) {
    const float* x      = (const float*)d_in[0];
    const float* w      = (const float*)d_in[1];
    const float* bias   = (const float*)d_in[2];
    const float* gumbel = (const float*)d_in[3];
    float* out = (float*)d_out;

    char* ws = (char*)d_ws;
    float*    xsumT    = (float*)(ws + 0);                 //  2 MB  [T][N]
    float*    inv_norm = (float*)(ws + 2097152);           //  8 KB  [N]
    float*    adj      = (float*)(ws + 2105344);           // 16 MB  [N][N]
    ushort_t* nm       = (ushort_t*)(ws + 18882560);       //  8 MB  [N][N] bf16
    float*    W        = (float*)(ws + 27271168);          // 16 MB  [N][N]
    float*    dinv     = (float*)(ws + 44048384);          //  8 KB  [N]
    ushort_t* Wtn      = (ushort_t*)(ws + 44056576);       //  8 MB  [N][N] bf16 (transposed Wn)
    ushort_t* xwT      = (ushort_t*)(ws + 52445184);       // 16 MB  [B*T][N] bf16

    k_colsum <<<dim3(NN / 256, TT), 256, 0, stream>>>(x, xsumT);
    k_invnorm<<<dim3(NN / 256),     256, 0, stream>>>(xsumT, inv_norm);
    k_adj    <<<dim3(16, 16),       256, 0, stream>>>(xsumT, inv_norm, gumbel, adj);
    k_nmask  <<<dim3(64, 64),       256, 0, stream>>>(adj, nm);
    k_commonW<<<dim3(16, 16),       256, 0, stream>>>(nm, adj, W);
    k_dinv   <<<dim3(NN / 256),     256, 0, stream>>>(W, dinv);
    k_wtn    <<<dim3(32, 32),       256, 0, stream>>>(W, dinv, Wtn);
    k_xw     <<<dim3(16, 2, BB),    256, 0, stream>>>(w, x, xwT);
    k_out    <<<dim3(16, 32),       256, 0, stream>>>(xwT, Wtn, bias, out);
}

// Round 3
// 308.152 us; speedup vs baseline: 1.3613x; 1.3613x over previous
//
#include <hip/hip_runtime.h>

#define NN 2048
#define BB 16
#define TT 256

typedef unsigned short ushort_t;
typedef short bf16x8 __attribute__((ext_vector_type(8)));
typedef float f32x4 __attribute__((ext_vector_type(4)));

__device__ __forceinline__ ushort_t f2bf(float f) {
    unsigned u = __float_as_uint(f);
    return (ushort_t)((u + 0x7FFFu + ((u >> 16) & 1u)) >> 16);  // RNE
}

// async global->LDS, 16B per lane; LDS dest must be wave-uniform-base + lane*16
__device__ __forceinline__ void gload16(const void* g, void* l) {
    __builtin_amdgcn_global_load_lds((const __attribute__((address_space(1))) unsigned int*)g,
                                     (__attribute__((address_space(3))) unsigned int*)l,
                                     16, 0, 0);
}

// K1: xsumT[t][n] = sum_b x[b][t][n]; also ssq[n] += s^2 (for inv_norm)
__global__ __launch_bounds__(256) void k_colsum(const float* __restrict__ x,
                                                float* __restrict__ xsumT,
                                                float* __restrict__ ssq) {
    const int n = blockIdx.x * 256 + threadIdx.x;
    const int t = blockIdx.y;
    float s = 0.f;
#pragma unroll
    for (int b = 0; b < BB; b++) s += x[(size_t)(b * TT + t) * NN + n];
    xsumT[(size_t)t * NN + n] = s;
    atomicAdd(&ssq[n], s * s);
}

// K2: sim GEMM (fp32, K=256) + gumbel comparator -> adjb (0/1 bf16)
__global__ __launch_bounds__(256) void k_adj(const float* __restrict__ A,
                                             const float* __restrict__ ssq,
                                             const float* __restrict__ gumbel,
                                             ushort_t* __restrict__ adjb) {
    __shared__ __align__(16) float As[8][128];
    __shared__ __align__(16) float Bs[8][128];
    const int m0 = blockIdx.y * 128, n0 = blockIdx.x * 128;
    const int tid = threadIdx.x;
    const int tx = tid & 15, ty = tid >> 4;
    const int lr = tid >> 5, lc = (tid & 31) * 4;
    float acc[8][8];
#pragma unroll
    for (int i = 0; i < 8; i++)
#pragma unroll
        for (int j = 0; j < 8; j++) acc[i][j] = 0.f;
    for (int k0 = 0; k0 < TT; k0 += 8) {
        __syncthreads();
        gload16(&A[(size_t)(k0 + lr) * NN + m0 + lc], &As[lr][lc]);
        gload16(&A[(size_t)(k0 + lr) * NN + n0 + lc], &Bs[lr][lc]);
        __syncthreads();
#pragma unroll
        for (int kk = 0; kk < 8; kk++) {
            float a[8], b[8];
            *(float4*)&a[0] = *(const float4*)&As[kk][ty * 8];
            *(float4*)&a[4] = *(const float4*)&As[kk][ty * 8 + 4];
            *(float4*)&b[0] = *(const float4*)&Bs[kk][tx * 8];
            *(float4*)&b[4] = *(const float4*)&Bs[kk][tx * 8 + 4];
#pragma unroll
            for (int i = 0; i < 8; i++)
#pragma unroll
                for (int j = 0; j < 8; j++) acc[i][j] = fmaf(a[i], b[j], acc[i][j]);
        }
    }
#pragma unroll
    for (int i = 0; i < 8; i++) {
        const int gi = m0 + ty * 8 + i;
        const float si = ssq[gi];
        const float invi = (si > 0.f) ? rsqrtf(si) : 0.f;
#pragma unroll
        for (int j = 0; j < 8; j++) {
            const int gj = n0 + tx * 8 + j;
            const float sj = ssq[gj];
            const float invj = (sj > 0.f) ? rsqrtf(sj) : 0.f;
            const float dot = acc[i][j] * invi * invj;
            const size_t fl = (size_t)gi * NN + gj;
            const float2 g = *(const float2*)&gumbel[2 * fl];
            adjb[fl] = (dot > g.y - g.x) ? (ushort_t)0x3F80 : (ushort_t)0;
        }
    }
}

// K3: nmask = adj | adjT | I  as bf16 (exact 0/1)
__global__ __launch_bounds__(256) void k_nmask(const ushort_t* __restrict__ adjb,
                                               ushort_t* __restrict__ nm) {
    __shared__ ushort_t tt[32][33];
    const int J = blockIdx.x * 32, I = blockIdx.y * 32;
    const int c = threadIdx.x & 31, r0 = threadIdx.x >> 5;  // 8 row-groups
#pragma unroll
    for (int r = r0; r < 32; r += 8) tt[r][c] = adjb[(size_t)(J + r) * NN + I + c];
    __syncthreads();
#pragma unroll
    for (int r = r0; r < 32; r += 8) {
        const int gi = I + r, gj = J + c;
        const bool on = (gi == gj) || adjb[(size_t)gi * NN + gj] || tt[c][r];
        nm[(size_t)gi * NN + gj] = on ? (ushort_t)0x3F80 : (ushort_t)0;
    }
}

// K4: common = nmask @ nmask (bf16 MFMA, integer-exact), fused
//     W[i][j] = adj * (common>1) * common^2   (max_common cancels in Wn)
//     + deg[j] partial sums via atomicAdd (deg must be zeroed beforehand)
__global__ __launch_bounds__(256) void k_commonW(const ushort_t* __restrict__ nm,
                                                 const ushort_t* __restrict__ adjb,
                                                 float* __restrict__ W,
                                                 float* __restrict__ deg) {
    __shared__ __align__(16) ushort_t As[128][32];
    __shared__ __align__(16) ushort_t Bs[128][32];
    const int m0 = blockIdx.y * 128, n0 = blockIdx.x * 128;
    const int tid = threadIdx.x;
    const int lane = tid & 63, wave = tid >> 6;
    const int wr = wave >> 1, wc = wave & 1;
    f32x4 acc[4][4];
#pragma unroll
    for (int i = 0; i < 4; i++)
#pragma unroll
        for (int j = 0; j < 4; j++) acc[i][j] = (f32x4){0.f, 0.f, 0.f, 0.f};
    const int r0 = tid >> 2, kc = (tid & 3) * 8;
    for (int k0 = 0; k0 < NN; k0 += 32) {
        __syncthreads();
        gload16(&nm[(size_t)(m0 + r0) * NN + k0 + kc], &As[r0][kc]);
        gload16(&nm[(size_t)(n0 + r0) * NN + k0 + kc], &Bs[r0][kc]);
        gload16(&nm[(size_t)(m0 + r0 + 64) * NN + k0 + kc], &As[r0 + 64][kc]);
        gload16(&nm[(size_t)(n0 + r0 + 64) * NN + k0 + kc], &Bs[r0 + 64][kc]);
        __syncthreads();
        const int lr = lane & 15, kg = (lane >> 4) * 8;
        bf16x8 af[4], bff[4];
#pragma unroll
        for (int f = 0; f < 4; f++) {
            af[f]  = *(const bf16x8*)&As[wr * 64 + f * 16 + lr][kg];
            bff[f] = *(const bf16x8*)&Bs[wc * 64 + f * 16 + lr][kg];
        }
#pragma unroll
        for (int i = 0; i < 4; i++)
#pragma unroll
            for (int j = 0; j < 4; j++)
                acc[i][j] = __builtin_amdgcn_mfma_f32_16x16x32_bf16(af[i], bff[j], acc[i][j], 0, 0, 0);
    }
    const int lr = lane & 15, rg = (lane >> 4) * 4;
#pragma unroll
    for (int j = 0; j < 4; j++) {
        const int gj = n0 + wc * 64 + j * 16 + lr;
        float psum = 0.f;
#pragma unroll
        for (int i = 0; i < 4; i++)
#pragma unroll
            for (int r = 0; r < 4; r++) {
                const int gi = m0 + wr * 64 + i * 16 + rg + r;
                const float cv = acc[i][j][r];
                const size_t fl = (size_t)gi * NN + gj;
                const float wv = (cv > 1.0f && adjb[fl]) ? cv * cv : 0.f;
                W[fl] = wv;
                psum += wv;
            }
        atomicAdd(&deg[gj], psum);
    }
}

// K5: Wtn[d][s] = bf16( dinv[s] * W[s][d] * dinv[d] ), dinv computed inline from deg
__global__ __launch_bounds__(256) void k_wtn(const float* __restrict__ W,
                                             const float* __restrict__ deg,
                                             ushort_t* __restrict__ Wtn) {
    __shared__ float tt[64][65];
    const int S0 = blockIdx.x * 64, D0 = blockIdx.y * 64;
    const int c = threadIdx.x & 63, r0 = threadIdx.x >> 6;  // 4 row-groups
#pragma unroll
    for (int r = r0; r < 64; r += 4) tt[r][c] = W[(size_t)(S0 + r) * NN + D0 + c];
    __syncthreads();
    const float dgs = deg[S0 + c];
    const float ds = (dgs > 0.f) ? rsqrtf(dgs) : 0.f;
#pragma unroll
    for (int r = r0; r < 64; r += 4) {
        const int d = D0 + r;
        const float dgd = deg[d];
        const float dd = (dgd > 0.f) ? rsqrtf(dgd) : 0.f;
        Wtn[(size_t)d * NN + S0 + c] = f2bf(tt[c][r] * ds * dd);
    }
}

// K6: transpose+convert x[b][t][n] fp32 -> xT[b][n][t] bf16
__global__ __launch_bounds__(256) void k_xt(const float* __restrict__ x,
                                            ushort_t* __restrict__ xT) {
    __shared__ float tile[64][65];
    const int b = blockIdx.z, t0 = blockIdx.y * 64, n0 = blockIdx.x * 64;
    const int c = threadIdx.x & 63, r0 = threadIdx.x >> 6;
#pragma unroll
    for (int r = r0; r < 64; r += 4)
        tile[r][c] = x[(size_t)(b * TT + t0 + r) * NN + n0 + c];
    __syncthreads();
#pragma unroll
    for (int r = r0; r < 64; r += 4)
        xT[(size_t)(b * NN + n0 + r) * TT + t0 + c] = f2bf(tile[c][r]);
}

// K7: wT[o][t] = bf16(w[t][o])
__global__ __launch_bounds__(256) void k_wt(const float* __restrict__ w,
                                            ushort_t* __restrict__ wT) {
    __shared__ float tile[64][65];
    const int t0 = blockIdx.y * 64, o0 = blockIdx.x * 64;
    const int c = threadIdx.x & 63, r0 = threadIdx.x >> 6;
#pragma unroll
    for (int r = r0; r < 64; r += 4)
        tile[r][c] = w[(size_t)(t0 + r) * TT + o0 + c];
    __syncthreads();
#pragma unroll
    for (int r = r0; r < 64; r += 4)
        wT[(size_t)(o0 + r) * TT + t0 + c] = f2bf(tile[c][r]);
}

// K8: xwT[b][o][n] = sum_t wT[o][t] * xT[b][n][t]  (bf16 MFMA), stored bf16
__global__ __launch_bounds__(256) void k_xw(const ushort_t* __restrict__ wT,
                                            const ushort_t* __restrict__ xT,
                                            ushort_t* __restrict__ xwT) {
    __shared__ __align__(16) ushort_t As[128][32];
    __shared__ __align__(16) ushort_t Bs[128][32];
    const int b = blockIdx.z;
    const ushort_t* __restrict__ Bg = xT + (size_t)b * NN * TT;
    const int m0 = blockIdx.y * 128, n0 = blockIdx.x * 128;
    const int tid = threadIdx.x;
    const int lane = tid & 63, wave = tid >> 6;
    const int wr = wave >> 1, wc = wave & 1;
    f32x4 acc[4][4];
#pragma unroll
    for (int i = 0; i < 4; i++)
#pragma unroll
        for (int j = 0; j < 4; j++) acc[i][j] = (f32x4){0.f, 0.f, 0.f, 0.f};
    const int r0 = tid >> 2, kc = (tid & 3) * 8;
    for (int k0 = 0; k0 < TT; k0 += 32) {
        __syncthreads();
        gload16(&wT[(size_t)(m0 + r0) * TT + k0 + kc], &As[r0][kc]);
        gload16(&Bg[(size_t)(n0 + r0) * TT + k0 + kc], &Bs[r0][kc]);
        gload16(&wT[(size_t)(m0 + r0 + 64) * TT + k0 + kc], &As[r0 + 64][kc]);
        gload16(&Bg[(size_t)(n0 + r0 + 64) * TT + k0 + kc], &Bs[r0 + 64][kc]);
        __syncthreads();
        const int lr = lane & 15, kg = (lane >> 4) * 8;
        bf16x8 af[4], bff[4];
#pragma unroll
        for (int f = 0; f < 4; f++) {
            af[f]  = *(const bf16x8*)&As[wr * 64 + f * 16 + lr][kg];
            bff[f] = *(const bf16x8*)&Bs[wc * 64 + f * 16 + lr][kg];
        }
#pragma unroll
        for (int i = 0; i < 4; i++)
#pragma unroll
            for (int j = 0; j < 4; j++)
                acc[i][j] = __builtin_amdgcn_mfma_f32_16x16x32_bf16(af[i], bff[j], acc[i][j], 0, 0, 0);
    }
    const int lr = lane & 15, rg = (lane >> 4) * 4;
#pragma unroll
    for (int i = 0; i < 4; i++)
#pragma unroll
        for (int j = 0; j < 4; j++)
#pragma unroll
            for (int r = 0; r < 4; r++) {
                const int o = m0 + wr * 64 + i * 16 + rg + r;
                const int n = n0 + wc * 64 + j * 16 + lr;
                xwT[((size_t)b * TT + o) * NN + n] = f2bf(acc[i][j][r]);
            }
}

// K9: out[bt][d] = sum_s xwT[bt][s] * Wtn[d][s] + bias[bt%T]  (bf16 MFMA)
__global__ __launch_bounds__(256) void k_out(const ushort_t* __restrict__ xwT,
                                             const ushort_t* __restrict__ Wtn,
                                             const float* __restrict__ bias,
                                             float* __restrict__ out) {
    __shared__ __align__(16) ushort_t As[128][32];
    __shared__ __align__(16) ushort_t Bs[128][32];
    const int m0 = blockIdx.y * 128, n0 = blockIdx.x * 128;
    const int tid = threadIdx.x;
    const int lane = tid & 63, wave = tid >> 6;
    const int wr = wave >> 1, wc = wave & 1;
    f32x4 acc[4][4];
#pragma unroll
    for (int i = 0; i < 4; i++)
#pragma unroll
        for (int j = 0; j < 4; j++) acc[i][j] = (f32x4){0.f, 0.f, 0.f, 0.f};
    const int r0 = tid >> 2, kc = (tid & 3) * 8;
    for (int k0 = 0; k0 < NN; k0 += 32) {
        __syncthreads();
        gload16(&xwT[(size_t)(m0 + r0) * NN + k0 + kc], &As[r0][kc]);
        gload16(&Wtn[(size_t)(n0 + r0) * NN + k0 + kc], &Bs[r0][kc]);
        gload16(&xwT[(size_t)(m0 + r0 + 64) * NN + k0 + kc], &As[r0 + 64][kc]);
        gload16(&Wtn[(size_t)(n0 + r0 + 64) * NN + k0 + kc], &Bs[r0 + 64][kc]);
        __syncthreads();
        const int lr = lane & 15, kg = (lane >> 4) * 8;
        bf16x8 af[4], bff[4];
#pragma unroll
        for (int f = 0; f < 4; f++) {
            af[f]  = *(const bf16x8*)&As[wr * 64 + f * 16 + lr][kg];
            bff[f] = *(const bf16x8*)&Bs[wc * 64 + f * 16 + lr][kg];
        }
#pragma unroll
        for (int i = 0; i < 4; i++)
#pragma unroll
            for (int j = 0; j < 4; j++)
                acc[i][j] = __builtin_amdgcn_mfma_f32_16x16x32_bf16(af[i], bff[j], acc[i][j], 0, 0, 0);
    }
    const int lr = lane & 15, rg = (lane >> 4) * 4;
#pragma unroll
    for (int i = 0; i < 4; i++)
#pragma unroll
        for (int j = 0; j < 4; j++)
#pragma unroll
            for (int r = 0; r < 4; r++) {
                const int gm = m0 + wr * 64 + i * 16 + rg + r;  // bt
                const int gd = n0 + wc * 64 + j * 16 + lr;      // node d
                out[(size_t)gm * NN + gd] = acc[i][j][r] + bias[gm & (TT - 1)];
            }
}

extern "C" void kernel_launch(void* const* d_in, const int* in_sizes, int n_in,
                              void* d_out, int out_size, void* d_ws, size_t ws_size,
                              hipStream_t stream) {
    const float* x      = (const float*)d_in[0];
    const float* w      = (const float*)d_in[1];
    const float* bias   = (const float*)d_in[2];
    const float* gumbel = (const float*)d_in[3];
    float* out = (float*)d_out;

    char* ws = (char*)d_ws;
    // layout (bytes); xT aliases adjb+nm (dead after k_commonW); xwT aliases W (dead after k_wtn)
    float*    xsumT = (float*)(ws + 0);              //  2 MB [T][N] f32
    float*    ssq   = (float*)(ws + 2097152);        //  8 KB [N]
    float*    deg   = (float*)(ws + 2105344);        //  8 KB [N]
    ushort_t* adjb  = (ushort_t*)(ws + 2113536);     //  8 MB [N][N] bf16
    ushort_t* nm    = (ushort_t*)(ws + 10502144);    //  8 MB [N][N] bf16
    ushort_t* xT    = (ushort_t*)(ws + 2113536);     // 16 MB [B][N][T] bf16 (aliases adjb+nm)
    float*    W     = (float*)(ws + 18890752);       // 16 MB [N][N] f32
    ushort_t* xwT   = (ushort_t*)(ws + 18890752);    // 16 MB [B*T][N] bf16 (aliases W)
    ushort_t* Wtn   = (ushort_t*)(ws + 35667968);    //  8 MB [N][N] bf16
    ushort_t* wT    = (ushort_t*)(ws + 44056576);    // 128 KB [T][T] bf16

    hipMemsetAsync(ws + 2097152, 0, 16384, stream);  // zero ssq + deg

    k_colsum <<<dim3(NN / 256, TT), 256, 0, stream>>>(x, xsumT, ssq);
    k_adj    <<<dim3(16, 16),       256, 0, stream>>>(xsumT, ssq, gumbel, adjb);
    k_nmask  <<<dim3(64, 64),       256, 0, stream>>>(adjb, nm);
    k_commonW<<<dim3(16, 16),       256, 0, stream>>>(nm, adjb, W, deg);
    k_wtn    <<<dim3(32, 32),       256, 0, stream>>>(W, deg, Wtn);
    k_xt     <<<dim3(32, 4, BB),    256, 0, stream>>>(x, xT);
    k_wt     <<<dim3(4, 4),         256, 0, stream>>>(w, wT);
    k_xw     <<<dim3(16, 2, BB),    256, 0, stream>>>(wT, xT, xwT);
    k_out    <<<dim3(16, 32),       256, 0, stream>>>(xwT, Wtn, bias, out);
}